// Round 8
// baseline (327.990 us; speedup 1.0000x reference)
//
#include <hip/hip_runtime.h>
#include <hip/hip_bf16.h>
#include <stdint.h>

#define IN_F 1024
#define OUT_F 1024
#define NB 8
#define KDIM (IN_F + IN_F * NB)  /* 9216 */
#define NROWS 4096
#define SLICE_ELEMS (NROWS * OUT_F)
#define PREP_BLOCKS ((NROWS * IN_F) / 256)        /* 16384 */
#define WCONV_BLOCKS ((OUT_F * KDIM) / (4 * 256)) /* 9216  */

typedef __attribute__((ext_vector_type(8))) short bf16x8;
typedef __attribute__((ext_vector_type(4))) short bf16x4;
typedef __attribute__((ext_vector_type(4))) float f32x4;

// Closed-form uniform cubic B-spline (knots t_j = -2.2 + 0.4j; EPS=1e-8 shift is
// far below bf16 rounding). For x in [t_i,t_{i+1}): 4 nonzero cardinal cubics.
__device__ __forceinline__ void bspline8(float x, float b8[8]) {
  float u = (x + 2.2f) * 2.5f;  // (x - t0)/h
  bool in = (u >= 0.0f) && (u < 11.0f);
  float uc = fminf(fmaxf(u, 0.0f), 10.99f);
  int i = (int)uc;
  float f = uc - (float)i;
  float g = 1.0f - f;
  float f2 = f * f, f3 = f2 * f;
  const float s = 1.0f / 6.0f;
  float v0 = f3 * s;
  float v1 = (-3.0f * f3 + 3.0f * f2 + 3.0f * f + 1.0f) * s;
  float v2 = (3.0f * f3 - 6.0f * f2 + 4.0f) * s;
  float v3 = g * g * g * s;
#pragma unroll
  for (int j = 0; j < 8; ++j) {
    int d = i - j;
    float r = (d == 0) ? v0 : (d == 1) ? v1 : (d == 2) ? v2 : (d == 3) ? v3 : 0.0f;
    b8[j] = in ? r : 0.0f;
  }
}

// Fused prep (A build) + weight conversion, branch on blockIdx (block-uniform).
__global__ void prep_all_kernel(const float* __restrict__ x, const float* __restrict__ bw,
                                const float* __restrict__ sw, __hip_bfloat16* __restrict__ A,
                                __hip_bfloat16* __restrict__ W) {
  if (blockIdx.x < PREP_BLOCKS) {
    int idx = blockIdx.x * 256 + threadIdx.x;
    int n = idx >> 10;
    int i = idx & 1023;
    float xv = x[idx];
    float sl = xv / (1.0f + __expf(-xv));
    __hip_bfloat16* row = A + (size_t)n * KDIM;
    row[i] = __float2bfloat16(sl);
    float b8[8];
    bspline8(xv, b8);
    alignas(16) __hip_bfloat16 tmp[8];
#pragma unroll
    for (int c = 0; c < 8; ++c) tmp[c] = __float2bfloat16(b8[c]);
    *(bf16x8*)(row + IN_F + i * 8) = *(const bf16x8*)tmp;
  } else {
    int v = (blockIdx.x - PREP_BLOCKS) * 256 + threadIdx.x;
    int e = v * 4;
    int o = e / KDIM;
    int k = e - o * KDIM;
    float4 val = (k < IN_F) ? *(const float4*)(bw + o * IN_F + k)
                            : *(const float4*)(sw + (size_t)o * (IN_F * NB) + (k - IN_F));
    alignas(8) __hip_bfloat16 t[4];
    t[0] = __float2bfloat16(val.x);
    t[1] = __float2bfloat16(val.y);
    t[2] = __float2bfloat16(val.z);
    t[3] = __float2bfloat16(val.w);
    *(bf16x4*)(W + e) = *(const bf16x4*)t;
  }
}

// ---------------------------------------------------------------------------
// R8: A-fragments DIRECT TO REGISTERS (no LDS for A). Rationale: R2/R3/R6/R7
// schedule variants all plateau 100-122 us; per-tile pipe budget shows LDS was
// the binding resource (192 ds_read_b128 ~2300cyc + 770 write vs MFMA 2480)
// and the barrier lockstep serialized them. A's MFMA fragment (lane: row=l&15,
// k=(l>>4)*8) is loadable as one global bf16x8/lane: lanes {0,16,32,48} cover
// one row's 64B contiguous -> full cache lines. 4x warp redundancy moves from
// LDS to L1/L2. LDS now holds only B (2 slots x 32 KiB): per-tile LDS ~1024cyc,
// MFMA 2480 is the new critical pipe.
// Sync: ONE barrier per K-tile (B slot handoff). All A/B-frag waits are
// compiler-inserted counted vmcnt/lgkm (m97: compiler does this exactly).
// Hand vmcnt(8) before the barrier: outstanding = 4 B-stage gloads (oldest)
// + 8 a03(t+1) loads -> drains exactly the stages, keeps A in flight.
// WAR ledger: B(t+1)->slot p^1 issued after the tile(t-1) barrier, behind
// which ALL waves' slot-p^1 ds_reads (tile t-1) retired (each wave's pre-q01
// lgkm0 precedes its barrier). a03(t+1) loads issued after q01 (a03 last use);
// a47(t) issued at tile start (last use prev q11, earlier in program order).
// Epilogue: split-K via f32 atomicAdd directly to out (harness memsets out=0
// per iter); z==0 adds bias. Removes P partials + reduce kernel (~84 MB).
// ---------------------------------------------------------------------------
__global__ __launch_bounds__(512, 2) void gemm9_kernel(const __hip_bfloat16* __restrict__ A,
                                                       const __hip_bfloat16* __restrict__ W,
                                                       float* __restrict__ out,
                                                       const float* __restrict__ bias,
                                                       int kslice) {
  __shared__ __hip_bfloat16 lB[2][16384];
  const int tid = threadIdx.x;
  const int wave = tid >> 6;
  const int lane = tid & 63;
  const int warp_m = wave >> 2;  // 0..1 -> 128-row half
  const int warp_n = wave & 3;   // 0..3 -> 64-col quarter
  const int bm = blockIdx.x * 256;
  const int bn = blockIdx.y * 256;
  const int z = blockIdx.z;

  const int kbeg = z * kslice;
  const int NT = kslice >> 6;  // K-tiles of 64
  const int NIT = NT >> 1;     // pair-unrolled
  const int srow = lane & 15;
  const int skc = (lane >> 4) * 8;
  const int r = lane & 15;
  const int quad = lane >> 4;

  // Per-lane A row bases for the 8 M-subtiles this wave owns (frag t of a03 is
  // aRow[t], frag t of a47 is aRow[4+t]).
  const __hip_bfloat16* aRow[8];
#pragma unroll
  for (int t = 0; t < 8; ++t)
    aRow[t] = A + (size_t)(bm + warp_m * 128 + t * 16 + (lane & 15)) * KDIM + kbeg +
              ((lane >> 4) * 8);

  // B staging source rows (per-lane gather into fragment-ordered LDS).
  const __hip_bfloat16* rowB[2];
  rowB[0] = W + (size_t)(bn + (0 * 8 + wave) * 16 + srow) * KDIM + kbeg + skc;
  rowB[1] = W + (size_t)(bn + (1 * 8 + wave) * 16 + srow) * KDIM + kbeg + skc;

  f32x4 acc[8][4];
#pragma unroll
  for (int a = 0; a < 8; ++a)
#pragma unroll
    for (int b = 0; b < 4; ++b) acc[a][b] = (f32x4){0.f, 0.f, 0.f, 0.f};

#define GLOAD(SRC, DST)                                                                      \
  __builtin_amdgcn_global_load_lds((const __attribute__((address_space(1))) void*)(SRC),     \
                                   (__attribute__((address_space(3))) void*)(DST), 16, 0, 0)

  // Stage B half HID (0/1) of TILE into SLOT (2 gloads; clamped tail rewrite).
#define STAGE_B(TILE, HID, SLOT)                                          \
  do {                                                                    \
    const int tu_ = (TILE);                                               \
    const int ts_ = tu_ < NT ? tu_ : NT - 1;                              \
    const __hip_bfloat16* s_ = rowB[(HID)] + (size_t)ts_ * 64;            \
    __hip_bfloat16* d_ = &lB[(SLOT)][(((HID) * 8 + wave) * 2 + 0) * 512]; \
    GLOAD(s_, d_);                                                        \
    GLOAD(s_ + 32, d_ + 512);                                             \
  } while (0)

  bf16x8 a03[4][2], a47[4][2], b01[2][2], b23[2][2];

#define LOAD_A03(KOFF)                                                       \
  do {                                                                       \
    _Pragma("unroll") for (int t = 0; t < 4; ++t)                            \
    _Pragma("unroll") for (int s = 0; s < 2; ++s)                            \
        a03[t][s] = *(const bf16x8*)(aRow[t] + (KOFF) + s * 32);             \
  } while (0)
#define LOAD_A47(KOFF)                                                       \
  do {                                                                       \
    _Pragma("unroll") for (int t = 0; t < 4; ++t)                            \
    _Pragma("unroll") for (int s = 0; s < 2; ++s)                            \
        a47[t][s] = *(const bf16x8*)(aRow[4 + t] + (KOFF) + s * 32);         \
  } while (0)
#define LOAD_B01(SLOT)                                                                      \
  do {                                                                                      \
    _Pragma("unroll") for (int u = 0; u < 2; ++u) {                                         \
      b01[u][0] = *(const bf16x8*)&lB[(SLOT)][((warp_n * 4 + u) * 2 + 0) * 512 + lane * 8]; \
      b01[u][1] = *(const bf16x8*)&lB[(SLOT)][((warp_n * 4 + u) * 2 + 1) * 512 + lane * 8]; \
    }                                                                                       \
  } while (0)
#define LOAD_B23(SLOT)                                                                      \
  do {                                                                                      \
    _Pragma("unroll") for (int u = 0; u < 2; ++u) {                                         \
      b23[u][0] =                                                                           \
          *(const bf16x8*)&lB[(SLOT)][((warp_n * 4 + 2 + u) * 2 + 0) * 512 + lane * 8];     \
      b23[u][1] =                                                                           \
          *(const bf16x8*)&lB[(SLOT)][((warp_n * 4 + 2 + u) * 2 + 1) * 512 + lane * 8];     \
    }                                                                                       \
  } while (0)

#define MFMA_QUAD(AF, BF, TM0, TN0)                                                          \
  do {                                                                                       \
    _Pragma("unroll") for (int tm = 0; tm < 4; ++tm)                                         \
    _Pragma("unroll") for (int tn = 0; tn < 2; ++tn)                                         \
    _Pragma("unroll") for (int s = 0; s < 2; ++s)                                            \
        acc[(TM0) + tm][(TN0) + tn] = __builtin_amdgcn_mfma_f32_16x16x32_bf16(               \
            AF[tm][s], BF[tn][s], acc[(TM0) + tm][(TN0) + tn], 0, 0, 0);                     \
  } while (0)

#define PIN() __builtin_amdgcn_sched_barrier(0)

  // One K-tile. P = slot (compile-time), T = tile index (runtime).
  // Region 1: issue a47(T), stage B(T+1)->P^1, ds_read b01/b23(P).
  // Region 2: q00,q10,q01 (compiler inserts exact vmcnt/lgkm waits).
  // Region 3: issue a03(T+1) (a03 regs free after q01), then q11.
  // Region 4: vmcnt(8) drains the 4 B-stages; raw barrier = slot handoff.
#define TILE_BODY(P, T)                                      \
  do {                                                       \
    const int koff_ = (T) * 64;                              \
    LOAD_A47(koff_);                                         \
    STAGE_B((T) + 1, 0, (P) ^ 1);                            \
    STAGE_B((T) + 1, 1, (P) ^ 1);                            \
    LOAD_B01(P);                                             \
    LOAD_B23(P);                                             \
    PIN();                                                   \
    __builtin_amdgcn_s_setprio(1);                           \
    MFMA_QUAD(a03, b01, 0, 0);                               \
    MFMA_QUAD(a47, b01, 4, 0);                               \
    MFMA_QUAD(a03, b23, 0, 2);                               \
    __builtin_amdgcn_s_setprio(0);                           \
    PIN();                                                   \
    {                                                        \
      const int tn_ = ((T) + 1 < NT) ? (T) + 1 : NT - 1;     \
      LOAD_A03(tn_ * 64);                                    \
    }                                                        \
    PIN();                                                   \
    __builtin_amdgcn_s_setprio(1);                           \
    MFMA_QUAD(a47, b23, 4, 2);                               \
    __builtin_amdgcn_s_setprio(0);                           \
    PIN();                                                   \
    asm volatile("s_waitcnt vmcnt(8)" ::: "memory");         \
    PIN();                                                   \
    __builtin_amdgcn_s_barrier();                            \
  } while (0)

  // ---- prologue: stage B(0)->slot0 [4 gloads], issue a03(0) [8 loads];
  //      vmcnt(8) lands the stages (a03 stays in flight); barrier. ----
  STAGE_B(0, 0, 0);
  STAGE_B(0, 1, 0);
  LOAD_A03(0);
  asm volatile("s_waitcnt vmcnt(8)" ::: "memory");
  PIN();
  __builtin_amdgcn_s_barrier();

  for (int i = 0; i < NIT; ++i) {
    TILE_BODY(0, 2 * i);
    TILE_BODY(1, 2 * i + 1);
  }
  asm volatile("s_waitcnt vmcnt(0)" ::: "memory");

#undef TILE_BODY
#undef STAGE_B
#undef GLOAD
#undef LOAD_A03
#undef LOAD_A47
#undef LOAD_B01
#undef LOAD_B23
#undef MFMA_QUAD
#undef PIN

  // Split-K epilogue: atomic accumulate into out. z==0 adds bias once.
  // C/D map: col=lane&15, row=quad*4+reg (m89-verified).
#pragma unroll
  for (int tm = 0; tm < 8; ++tm) {
#pragma unroll
    for (int tn = 0; tn < 4; ++tn) {
      const int col = bn + warp_n * 64 + tn * 16 + r;
      const float bv = (z == 0) ? bias[col] : 0.0f;
#pragma unroll
      for (int reg = 0; reg < 4; ++reg) {
        const int rowi = bm + warp_m * 128 + tm * 16 + quad * 4 + reg;
        atomicAdd(&out[(size_t)rowi * OUT_F + col], acc[tm][tn][reg] + bv);
      }
    }
  }
}

// Emergency fallback if ws is too small for A+W (fp32, slow but correct).
__global__ void kan_fallback(const float* __restrict__ x, const float* __restrict__ bw,
                             const float* __restrict__ bb, const float* __restrict__ sw,
                             float* __restrict__ out) {
  __shared__ float act[KDIM];
  int n = blockIdx.x;
  for (int i = threadIdx.x; i < IN_F; i += 256) {
    float xv = x[(size_t)n * IN_F + i];
    act[i] = xv / (1.0f + __expf(-xv));
    float b8[8];
    bspline8(xv, b8);
#pragma unroll
    for (int c = 0; c < 8; ++c) act[IN_F + i * 8 + c] = b8[c];
  }
  __syncthreads();
  for (int o = threadIdx.x; o < OUT_F; o += 256) {
    float s = bb[o];
    const float* wbp = bw + (size_t)o * IN_F;
    for (int k = 0; k < IN_F; ++k) s += act[k] * wbp[k];
    const float* wsp = sw + (size_t)o * (IN_F * NB);
    for (int k = 0; k < IN_F * NB; ++k) s += act[IN_F + k] * wsp[k];
    out[(size_t)n * OUT_F + o] = s;
  }
}

extern "C" void kernel_launch(void* const* d_in, const int* in_sizes, int n_in, void* d_out,
                              int out_size, void* d_ws, size_t ws_size, hipStream_t stream) {
  const float* x = (const float*)d_in[0];
  const float* bw = (const float*)d_in[1];
  const float* bb = (const float*)d_in[2];
  const float* sw = (const float*)d_in[3];
  float* out = (float*)d_out;

  const size_t needA = (size_t)NROWS * KDIM * 2;  // 75.5 MB
  const size_t needW = (size_t)OUT_F * KDIM * 2;  // 18.9 MB
  if (ws_size < needA + needW) {
    kan_fallback<<<NROWS, 256, 0, stream>>>(x, bw, bb, sw, out);
    return;
  }
  __hip_bfloat16* A = (__hip_bfloat16*)d_ws;
  __hip_bfloat16* W = (__hip_bfloat16*)((char*)d_ws + needA);

  // S=4 split-K -> grid 16x4x4 = 256 blocks = 1/CU. kslice=2304, NT=36 (even).
  // Split-K accumulates via f32 atomicAdd into out (harness zeroes out/iter).
  prep_all_kernel<<<PREP_BLOCKS + WCONV_BLOCKS, 256, 0, stream>>>(x, bw, sw, A, W);
  gemm9_kernel<<<dim3(NROWS / 256, OUT_F / 256, 4), 512, 0, stream>>>(A, W, out, bb, KDIM / 4);
}

// Round 9
// 222.717 us; speedup vs baseline: 1.4727x; 1.4727x over previous
//
#include <hip/hip_runtime.h>
#include <hip/hip_bf16.h>
#include <stdint.h>

#define IN_F 1024
#define OUT_F 1024
#define NB 8
#define KDIM (IN_F + IN_F * NB)  /* 9216 */
#define NROWS 4096
#define SLICE_ELEMS (NROWS * OUT_F)
#define PREP_BLOCKS ((NROWS * IN_F) / 256)        /* 16384 */
#define WCONV_BLOCKS ((OUT_F * KDIM) / (4 * 256)) /* 9216  */

typedef __attribute__((ext_vector_type(8))) short bf16x8;
typedef __attribute__((ext_vector_type(4))) short bf16x4;
typedef __attribute__((ext_vector_type(4))) float f32x4;

// Closed-form uniform cubic B-spline (knots t_j = -2.2 + 0.4j; EPS=1e-8 shift is
// far below bf16 rounding). For x in [t_i,t_{i+1}): 4 nonzero cardinal cubics.
__device__ __forceinline__ void bspline8(float x, float b8[8]) {
  float u = (x + 2.2f) * 2.5f;  // (x - t0)/h
  bool in = (u >= 0.0f) && (u < 11.0f);
  float uc = fminf(fmaxf(u, 0.0f), 10.99f);
  int i = (int)uc;
  float f = uc - (float)i;
  float g = 1.0f - f;
  float f2 = f * f, f3 = f2 * f;
  const float s = 1.0f / 6.0f;
  float v0 = f3 * s;
  float v1 = (-3.0f * f3 + 3.0f * f2 + 3.0f * f + 1.0f) * s;
  float v2 = (3.0f * f3 - 6.0f * f2 + 4.0f) * s;
  float v3 = g * g * g * s;
#pragma unroll
  for (int j = 0; j < 8; ++j) {
    int d = i - j;
    float r = (d == 0) ? v0 : (d == 1) ? v1 : (d == 2) ? v2 : (d == 3) ? v3 : 0.0f;
    b8[j] = in ? r : 0.0f;
  }
}

// Fused prep (A build) + weight conversion, branch on blockIdx (block-uniform).
__global__ void prep_all_kernel(const float* __restrict__ x, const float* __restrict__ bw,
                                const float* __restrict__ sw, __hip_bfloat16* __restrict__ A,
                                __hip_bfloat16* __restrict__ W) {
  if (blockIdx.x < PREP_BLOCKS) {
    int idx = blockIdx.x * 256 + threadIdx.x;
    int n = idx >> 10;
    int i = idx & 1023;
    float xv = x[idx];
    float sl = xv / (1.0f + __expf(-xv));
    __hip_bfloat16* row = A + (size_t)n * KDIM;
    row[i] = __float2bfloat16(sl);
    float b8[8];
    bspline8(xv, b8);
    alignas(16) __hip_bfloat16 tmp[8];
#pragma unroll
    for (int c = 0; c < 8; ++c) tmp[c] = __float2bfloat16(b8[c]);
    *(bf16x8*)(row + IN_F + i * 8) = *(const bf16x8*)tmp;
  } else {
    int v = (blockIdx.x - PREP_BLOCKS) * 256 + threadIdx.x;
    int e = v * 4;
    int o = e / KDIM;
    int k = e - o * KDIM;
    float4 val = (k < IN_F) ? *(const float4*)(bw + o * IN_F + k)
                            : *(const float4*)(sw + (size_t)o * (IN_F * NB) + (k - IN_F));
    alignas(8) __hip_bfloat16 t[4];
    t[0] = __float2bfloat16(val.x);
    t[1] = __float2bfloat16(val.y);
    t[2] = __float2bfloat16(val.z);
    t[3] = __float2bfloat16(val.w);
    *(bf16x4*)(W + e) = *(const bf16x4*)t;
  }
}

// ---------------------------------------------------------------------------
// R9: barrier-minimal pipeline. All R2..R7 schedules (100-122us) kept per-phase
// barrier+lgkmcnt(0) lockstep; measured 6700cyc/tile vs MFMA floor 2480 ->
// the barriers serialize LDS reads against MFMA (m233). Restructure:
//   BK=32, TRIPLE-buffered LDS (3 x 32KB), fragments read ONE FULL K-TILE
//   AHEAD into register double-buffers -> MFMA(t) never waits on LDS;
//   ONE barrier per K-tile.
// Invariant at start of tile t: stage(t+1) landed; stage(t+2) in flight.
// Body(t): [reads(t+1).A -> other A-set (8 ds); stage(t+3) (4 gloads);
//   32 MFMA on cur regs (compiler lgkm-counts past the 8 new reads);
//   reads(t+1).B -> B-set (4 ds, WAR after last B-use); lgkm0; vmcnt(4); bar].
// WAR ledger: stage(t+3)->slot t%3; its readers (tile-t frags) were ds_read
// during t-1 and retired before the end-of-(t-1) barrier (own-wave lgkm0).
// vmcnt(4) at end of t: in flight = stage(t+2)[4, older] + stage(t+3)[4] ->
// drains exactly stage(t+2), keeping the pipe 2-deep. Tail: t+1/t+3 clamped
// to NT-1 (rewrites of identical data into dead-or-identical slots; counts
// uniform). 6-tile unroll: slot (t%3) x A-set parity (t&1) all compile-time.
// LDS fragment-ordered (prep pre-gathers) -> 0 bank conflicts; gload dest =
// wave-uniform base + lane*16 (legal). 96KB LDS -> 1 block/CU; grid 16x4x4.
// ---------------------------------------------------------------------------
__global__ __launch_bounds__(512, 2) void gemm10_kernel(const __hip_bfloat16* __restrict__ A,
                                                        const __hip_bfloat16* __restrict__ W,
                                                        float* __restrict__ dst,
                                                        const float* __restrict__ bias,
                                                        int kslice, int use_bias) {
  __shared__ __hip_bfloat16 lA[3][8192];
  __shared__ __hip_bfloat16 lB[3][8192];
  const int tid = threadIdx.x;
  const int wave = tid >> 6;
  const int lane = tid & 63;
  const int warp_m = wave >> 2;  // 0..1 -> 128-row half
  const int warp_n = wave & 3;   // 0..3 -> 64-col quarter
  const int bm = blockIdx.x * 256;
  const int bn = blockIdx.y * 256;
  const int z = blockIdx.z;

  float* __restrict__ d = dst + (size_t)z * SLICE_ELEMS;
  const int kbeg = z * kslice;
  const int NT = kslice >> 5;  // K-tiles of 32 (72 at S=4; divisible by 6)
  const int srow = lane & 15;
  const int skc = (lane >> 4) * 8;
  const int r = lane & 15;
  const int quad = lane >> 4;

  const __hip_bfloat16* rowA[2];
  const __hip_bfloat16* rowB[2];
  rowA[0] = A + (size_t)(bm + (0 * 8 + wave) * 16 + srow) * KDIM + kbeg + skc;
  rowA[1] = A + (size_t)(bm + (1 * 8 + wave) * 16 + srow) * KDIM + kbeg + skc;
  rowB[0] = W + (size_t)(bn + (0 * 8 + wave) * 16 + srow) * KDIM + kbeg + skc;
  rowB[1] = W + (size_t)(bn + (1 * 8 + wave) * 16 + srow) * KDIM + kbeg + skc;

  f32x4 acc[8][4];
#pragma unroll
  for (int a = 0; a < 8; ++a)
#pragma unroll
    for (int b = 0; b < 4; ++b) acc[a][b] = (f32x4){0.f, 0.f, 0.f, 0.f};

#define GLOAD(SRC, DST)                                                                      \
  __builtin_amdgcn_global_load_lds((const __attribute__((address_space(1))) void*)(SRC),     \
                                   (__attribute__((address_space(3))) void*)(DST), 16, 0, 0)

  // Stage K-tile TILE (clamped) into SLOT: A halves h=0,1 + B halves (4 gloads).
#define STAGE_TILE(TILE, SLOT)                                            \
  do {                                                                    \
    const int tu_ = (TILE);                                               \
    const int ts_ = tu_ < NT ? tu_ : NT - 1;                              \
    const size_t ko_ = (size_t)ts_ * 32;                                  \
    GLOAD(rowA[0] + ko_, &lA[(SLOT)][(0 * 8 + wave) * 512]);              \
    GLOAD(rowA[1] + ko_, &lA[(SLOT)][(1 * 8 + wave) * 512]);              \
    GLOAD(rowB[0] + ko_, &lB[(SLOT)][(0 * 8 + wave) * 512]);              \
    GLOAD(rowB[1] + ko_, &lB[(SLOT)][(1 * 8 + wave) * 512]);              \
  } while (0)

  bf16x8 a0[8], a1[8], bfr[4];

  // Read the 8 A-fragments of slot SLOT into set DST (8 x ds_read_b128).
#define LOAD_A(DST, SLOT)                                                        \
  do {                                                                           \
    _Pragma("unroll") for (int t = 0; t < 8; ++t)                                \
        DST[t] = *(const bf16x8*)&lA[(SLOT)][(warp_m * 8 + t) * 512 + lane * 8]; \
  } while (0)
  // Read the 4 B-fragments of slot SLOT (4 x ds_read_b128).
#define LOAD_B(SLOT)                                                             \
  do {                                                                           \
    _Pragma("unroll") for (int u = 0; u < 4; ++u)                                \
        bfr[u] = *(const bf16x8*)&lB[(SLOT)][(warp_n * 4 + u) * 512 + lane * 8]; \
  } while (0)

#define MFMA_ALL(ACUR)                                                                       \
  do {                                                                                       \
    _Pragma("unroll") for (int tm = 0; tm < 8; ++tm)                                         \
    _Pragma("unroll") for (int tn = 0; tn < 4; ++tn)                                         \
        acc[tm][tn] =                                                                        \
            __builtin_amdgcn_mfma_f32_16x16x32_bf16(ACUR[tm], bfr[tn], acc[tm][tn], 0, 0, 0);\
  } while (0)

#define PIN() __builtin_amdgcn_sched_barrier(0)

  // Tile body. T runtime; SLN=(T+1)%3, SLS=T%3 compile-time; ACUR/ANXT = A sets.
#define TILE_BODY(T, SLN, SLS, ACUR, ANXT)                   \
  do {                                                       \
    LOAD_A(ANXT, SLN);  /* next tile's A; not used below */  \
    STAGE_TILE((T) + 3, SLS);                                \
    PIN();                                                   \
    __builtin_amdgcn_s_setprio(1);                           \
    MFMA_ALL(ACUR); /* waits counted lgkm; skips new reads */\
    __builtin_amdgcn_s_setprio(0);                           \
    PIN();                                                   \
    LOAD_B(SLN); /* WAR: after last bfr use */               \
    asm volatile("s_waitcnt lgkmcnt(0)" ::: "memory");       \
    PIN();                                                   \
    asm volatile("s_waitcnt vmcnt(4)" ::: "memory");         \
    PIN();                                                   \
    __builtin_amdgcn_s_barrier();                            \
  } while (0)

  // ---- prologue: stage tiles 0,1,2 -> slots 0,1,2; land 0,1 (keep 2 in
  //      flight); read tile-0 fragments. Matches loop invariant at t=0. ----
  STAGE_TILE(0, 0);
  STAGE_TILE(1, 1);
  STAGE_TILE(2, 2);
  asm volatile("s_waitcnt vmcnt(4)" ::: "memory");
  PIN();
  __builtin_amdgcn_s_barrier();
  LOAD_A(a0, 0);
  LOAD_B(0);
  PIN();

  const int nit = NT / 6;
  for (int i = 0; i < nit; ++i) {
    const int b = 6 * i;
    TILE_BODY(b + 0, 1, 0, a0, a1);
    TILE_BODY(b + 1, 2, 1, a1, a0);
    TILE_BODY(b + 2, 0, 2, a0, a1);
    TILE_BODY(b + 3, 1, 0, a1, a0);
    TILE_BODY(b + 4, 2, 1, a0, a1);
    TILE_BODY(b + 5, 0, 2, a1, a0);
  }
  asm volatile("s_waitcnt vmcnt(0)" ::: "memory");

#undef TILE_BODY
#undef STAGE_TILE
#undef GLOAD
#undef LOAD_A
#undef LOAD_B
#undef MFMA_ALL
#undef PIN

  // C/D map: col=lane&15, row=quad*4+reg (m89-verified).
#pragma unroll
  for (int tm = 0; tm < 8; ++tm) {
#pragma unroll
    for (int tn = 0; tn < 4; ++tn) {
      const int col = bn + warp_n * 64 + tn * 16 + r;
      const float bv = use_bias ? bias[col] : 0.0f;
#pragma unroll
      for (int reg = 0; reg < 4; ++reg) {
        const int rowi = bm + warp_m * 128 + tm * 16 + quad * 4 + reg;
        d[(size_t)rowi * OUT_F + col] = acc[tm][tn][reg] + bv;
      }
    }
  }
}

// out = bias + sum_s partial[s], float4 per thread.
__global__ void reduce_kernel(const float* __restrict__ P, const float* __restrict__ bias,
                              float* __restrict__ out, int S) {
  int v = blockIdx.x * 256 + threadIdx.x;
  int e = v * 4;
  int o = e & (OUT_F - 1);
  float4 acc = *(const float4*)(bias + o);
  for (int s = 0; s < S; ++s) {
    float4 p = *(const float4*)(P + (size_t)s * SLICE_ELEMS + e);
    acc.x += p.x;
    acc.y += p.y;
    acc.z += p.z;
    acc.w += p.w;
  }
  *(float4*)(out + e) = acc;
}

// Emergency fallback if ws is too small for A+W (fp32, slow but correct).
__global__ void kan_fallback(const float* __restrict__ x, const float* __restrict__ bw,
                             const float* __restrict__ bb, const float* __restrict__ sw,
                             float* __restrict__ out) {
  __shared__ float act[KDIM];
  int n = blockIdx.x;
  for (int i = threadIdx.x; i < IN_F; i += 256) {
    float xv = x[(size_t)n * IN_F + i];
    act[i] = xv / (1.0f + __expf(-xv));
    float b8[8];
    bspline8(xv, b8);
#pragma unroll
    for (int c = 0; c < 8; ++c) act[IN_F + i * 8 + c] = b8[c];
  }
  __syncthreads();
  for (int o = threadIdx.x; o < OUT_F; o += 256) {
    float s = bb[o];
    const float* wbp = bw + (size_t)o * IN_F;
    for (int k = 0; k < IN_F; ++k) s += act[k] * wbp[k];
    const float* wsp = sw + (size_t)o * (IN_F * NB);
    for (int k = 0; k < IN_F * NB; ++k) s += act[IN_F + k] * wsp[k];
    out[(size_t)n * OUT_F + o] = s;
  }
}

extern "C" void kernel_launch(void* const* d_in, const int* in_sizes, int n_in, void* d_out,
                              int out_size, void* d_ws, size_t ws_size, hipStream_t stream) {
  const float* x = (const float*)d_in[0];
  const float* bw = (const float*)d_in[1];
  const float* bb = (const float*)d_in[2];
  const float* sw = (const float*)d_in[3];
  float* out = (float*)d_out;

  const size_t needA = (size_t)NROWS * KDIM * 2;  // 75.5 MB
  const size_t needW = (size_t)OUT_F * KDIM * 2;  // 18.9 MB
  const size_t sliceB = (size_t)SLICE_ELEMS * 4;  // 16.8 MB
  if (ws_size < needA + needW) {
    kan_fallback<<<NROWS, 256, 0, stream>>>(x, bw, bb, sw, out);
    return;
  }
  __hip_bfloat16* A = (__hip_bfloat16*)d_ws;
  __hip_bfloat16* W = (__hip_bfloat16*)((char*)d_ws + needA);
  float* P = (float*)((char*)d_ws + needA + needW);
  const size_t avail = ws_size - needA - needW;
  // S=4 -> 16x4x4 = 256 blocks = 1 block/CU (96 KB LDS). kslice=2304, NT=72.
  int S = (avail >= 4 * sliceB) ? 4 : (avail >= 2 * sliceB) ? 2 : 1;

  prep_all_kernel<<<PREP_BLOCKS + WCONV_BLOCKS, 256, 0, stream>>>(x, bw, sw, A, W);
  if (S == 1) {
    gemm10_kernel<<<dim3(NROWS / 256, OUT_F / 256, 1), 512, 0, stream>>>(A, W, out, bb, KDIM, 1);
  } else {
    gemm10_kernel<<<dim3(NROWS / 256, OUT_F / 256, S), 512, 0, stream>>>(A, W, P, bb, KDIM / S, 0);
    reduce_kernel<<<SLICE_ELEMS / (4 * 256), 256, 0, stream>>>(P, bb, out, S);
  }
}